// Round 4
// baseline (495.076 us; speedup 1.0000x reference)
//
#include <hip/hip_runtime.h>
#include <hip/hip_cooperative_groups.h>
#include <hip/hip_bf16.h>
#include <cstdint>
#include <cstddef>

namespace cg = cooperative_groups;

// Problem constants
constexpr int T = 8;
constexpr int C = 256;     // feature channels = GEMM K
constexpr int N = 4096;    // H*W pixels per frame
constexpr int CAP = 4232;  // packed rows per frame
constexpr float TEMP_INV = 14.285714285714286f;  // 1/0.07
constexpr float EPS = 1e-8f;

typedef __bf16 bf16;
typedef __bf16 bf16x8 __attribute__((ext_vector_type(8)));
typedef float floatx4 __attribute__((ext_vector_type(4)));

// async global->LDS, 16B per lane, wave-uniform LDS base + lane*16
__device__ __forceinline__ void async_copy16(const bf16* g, bf16* l) {
    __builtin_amdgcn_global_load_lds((const __attribute__((address_space(1))) void*)g,
                                     (__attribute__((address_space(3))) void*)l,
                                     16, 0, 0);
}

// LDS layout (phases are sequential; buffers alias):
//   sim:  a_lds [0,16384)  b_lds [16384,32768)  idx_s @34432
//   norm: tile [0,33024) partial @33024 rnorm @34048 rk @34304 bbase @34432
//   loss: fl/vv @0
// total 34816 B -> 4 blocks/CU by LDS; launch_bounds(256,3) -> <=168 VGPR.
__global__ __launch_bounds__(256, 3) void mega_kernel(
    const float* __restrict__ cur, const float* __restrict__ hist,
    const float* __restrict__ feat, float* __restrict__ out_labels,
    float* __restrict__ out_loss, char* __restrict__ ws)
{
    // workspace layout (host keeps in sync)
    bf16* fpack = (bf16*)ws;
    size_t off = (size_t)T * CAP * C * sizeof(bf16);
    float* negbuf = (float*)(ws + off); off += (size_t)T * N * 4;
    float* posc   = (float*)(ws + off); off += (size_t)T * N * 4;
    unsigned short* rankmap = (unsigned short*)(ws + off); off += (size_t)T * N * 2;
    float* dstat = (float*)(ws + off); off += 32 * 4;   // zeroed by host memset
    int* fgc = (int*)(ws + off); off += 8 * 4;          // zeroed
    int* bgc = (int*)(ws + off); off += 8 * 4;          // zeroed
    int* ctr = (int*)(ws + off); off += 8 * 4;          // zeroed
    int* nfg = (int*)(ws + off); off += 8 * 4;
    int* nbg = (int*)(ws + off);

    cg::grid_group grid = cg::this_grid();
    __shared__ __align__(16) char smem[34816];

    const int tid  = threadIdx.x;
    const int lane = tid & 63;
    const int G = gridDim.x;
    const int g0 = blockIdx.x * 256 + tid;
    const int gstep = G * 256;

    // ===== Phase A: dice partial sums (full-grid parallel) =====
    for (int p = g0; p < T * N; p += gstep) {
        int t = p >> 12;
        float c = cur[p], h = hist[p];
        float cb = c > 0.5f ? 1.f : 0.f;
        float hb = h > 0.5f ? 1.f : 0.f;
        float s1 = cb * hb, sc = cb, sh = hb;
        for (int o = 32; o > 0; o >>= 1) {
            s1 += __shfl_down(s1, o);
            sc += __shfl_down(sc, o);
            sh += __shfl_down(sh, o);
        }
        if (lane == 0) {
            atomicAdd(&dstat[t * 4 + 0], s1);
            atomicAdd(&dstat[t * 4 + 1], sc);
            atomicAdd(&dstat[t * 4 + 2], sh);
        }
    }
    __threadfence();
    grid.sync();
    __threadfence();

    // ===== Phase B: labels + rank compaction + negbuf zero + nfg/nbg + pad zero =====
    for (int p = g0; p < T * N; p += gstep) {
        int t = p >> 12;
        float e1 = dstat[t * 4 + 0];
        float sc = dstat[t * 4 + 1];
        float sh = dstat[t * 4 + 2];
        float e2 = sc + sh;
        float m1 = (2.f * e1 + EPS) / (e2 + EPS);
        float m2 = (e1 + EPS) / (e2 - e1 + EPS);
        float dev = 1.f - 0.5f * (m1 + m2);
        bool uc = (dev <= 0.0f);
        if ((p & (N - 1)) == 0) {
            int nf = (int)(uc ? sc : sh);
            nfg[t] = nf;
            nbg[t] = N - nf;
        }
        float lab = uc ? cur[p] : hist[p];
        out_labels[p] = lab;
        negbuf[p] = 0.f;
        bool fg = lab > 0.5f;
        unsigned long long b = __ballot(fg);
        unsigned long long lowmask = (lane == 63) ? 0x7fffffffffffffffull
                                                  : ((1ull << lane) - 1ull);
        int rank_fg = __popcll(b & lowmask);
        int rank_bg = __popcll((~b) & lowmask);
        int cnt_fg = __popcll(b);
        int base_fg = 0, base_bg = 0;
        if (lane == 0) {
            base_fg = atomicAdd(&fgc[t], cnt_fg);
            base_bg = atomicAdd(&bgc[t], 64 - cnt_fg);
        }
        base_fg = __shfl(base_fg, 0);
        base_bg = __shfl(base_bg, 0);
        int rank = fg ? (base_fg + rank_fg) : (base_bg + rank_bg);
        rankmap[p] = (unsigned short)(rank | (fg ? 0x8000 : 0));
    }
    {   // zero pad rows [N, CAP) of fpack: 8 frames x 136 rows x 32 chunks of 16B
        float4 z4 = make_float4(0.f, 0.f, 0.f, 0.f);
        for (int i = g0; i < T * 4352; i += gstep) {
            int t = i / 4352;
            int r = i - t * 4352;
            ((float4*)(fpack + ((size_t)t * CAP + N) * C))[r] = z4;
        }
    }
    __threadfence();
    grid.sync();
    __threadfence();

    // ===== Phase C: normalize + bf16 cast + swizzled compacted scatter (round-0 body) =====
    {
        bf16* tile = (bf16*)smem;                       // [64][258]
        float* partial = (float*)(smem + 33024);        // [256]
        float* rnorm_s = (float*)(smem + 34048);        // [64]
        unsigned short* rk_s = (unsigned short*)(smem + 34304);  // [64]
        int* bbase_s = (int*)(smem + 34432);
        for (int bb = blockIdx.x; bb < 512; bb += G) {
            __syncthreads();                            // protect tile reuse
            int t = bb >> 6;
            int n0 = (bb & 63) * 64;
            int lane63 = tid & 63;
            int w = tid >> 6;
            if (tid == 0) bbase_s[0] = (nfg[t] + 7) & ~7;
            if (tid < 64) rk_s[tid] = rankmap[t * N + n0 + tid];
            const float* fb = feat + (size_t)t * C * N;
            float ss = 0.f;
            #pragma unroll 16
            for (int it = 0; it < 64; ++it) {
                int c = w * 64 + it;
                float v = fb[(size_t)c * N + n0 + lane63];
                ss += v * v;
                tile[lane63 * 258 + c] = (bf16)v;
            }
            partial[tid] = ss;
            __syncthreads();
            if (tid < 64) {
                float s = partial[tid] + partial[tid + 64] + partial[tid + 128] + partial[tid + 192];
                float r = 1.f / fmaxf(sqrtf(s), 1e-12f);
                rnorm_s[tid] = r;
                unsigned short rk = rk_s[tid];
                if (rk & 0x8000) posc[t * N + (rk & 0x7fff)] = s * r * r;  // fg only
            }
            __syncthreads();
            int bbase = bbase_s[0];
            bf16* fp = fpack + (size_t)t * CAP * C;
            #pragma unroll
            for (int it = 0; it < 8; ++it) {
                int l = it * 256 + tid;
                int n = l >> 5;
                int c8 = l & 31;
                unsigned short rk = rk_s[n];
                int r_pack = (rk & 0x7fff) + ((rk & 0x8000) ? 0 : bbase);
                int slot = (c8 & ~7) | ((c8 & 7) ^ (r_pack & 7));   // swizzled store pos
                float r = rnorm_s[n];
                bf16x8 vin = *(const bf16x8*)&tile[n * 258 + c8 * 8];
                bf16x8 vo;
                for (int j = 0; j < 8; ++j) vo[j] = (bf16)((float)vin[j] * r);
                *(bf16x8*)(fp + (size_t)r_pack * C + slot * 8) = vo;
            }
        }
    }
    __threadfence();
    grid.sync();
    __threadfence();

    // ===== Phase D: sim GEMM + exp + row-sum, dynamic per-frame work stealing =====
    {
        int t = blockIdx.x & 7;            // frame pin (grid multiple of 8)
        int nfgt = nfg[t];
        int nbgt = nbg[t];
        int bbase = (nfgt + 7) & ~7;
        bf16* a_lds = (bf16*)smem;
        bf16* b_lds = (bf16*)(smem + 16384);
        int* idx_s = (int*)(smem + 34432);
        const bf16* fb = fpack + (size_t)t * CAP * C;
        int w = tid >> 6;
        int lrow = lane >> 3;
        int lchunk = lane & 7;
        int r0w = (w & 1) * 64;
        int c0w = (w >> 1) * 64;

        while (true) {
            __syncthreads();               // protect idx_s + LDS reuse
            if (tid == 0) idx_s[0] = atomicAdd(&ctr[t], 1);
            __syncthreads();
            int lt = idx_s[0];
            if (lt >= 1024) break;
            int rowbase = (lt >> 5) * 128;
            if (rowbase >= nfgt) break;    // rows grow with lt -> done
            int colbase = (lt & 31) * 128;
            if (colbase >= nbgt) continue;

            floatx4 acc[4][4];
            for (int i = 0; i < 4; ++i)
                for (int j = 0; j < 4; ++j)
                    acc[i][j] = (floatx4){0.f, 0.f, 0.f, 0.f};

            for (int ks = 0; ks < 4; ++ks) {
                int k0 = ks * 64;
                __syncthreads();
                for (int s = 0; s < 4; ++s) {
                    int q = w * 4 + s;
                    int ra = rowbase + q * 8 + lrow;
                    int rb = bbase + colbase + q * 8 + lrow;
                    async_copy16(fb + (size_t)ra * C + k0 + lchunk * 8, &a_lds[q * 512]);
                    async_copy16(fb + (size_t)rb * C + k0 + lchunk * 8, &b_lds[q * 512]);
                }
                __syncthreads();
                for (int kk = 0; kk < 64; kk += 32) {
                    int quad = lane >> 4;
                    int chread = (kk >> 3) + quad;
                    bf16x8 af[4], bfr[4];
                    for (int i = 0; i < 4; ++i) {
                        int r = r0w + 16 * i + (lane & 15);
                        int chs = chread ^ (r & 7);
                        af[i] = *(const bf16x8*)&a_lds[r * 64 + chs * 8];
                    }
                    for (int j = 0; j < 4; ++j) {
                        int cidx = c0w + 16 * j + (lane & 15);
                        int chs = chread ^ (cidx & 7);
                        bfr[j] = *(const bf16x8*)&b_lds[cidx * 64 + chs * 8];
                    }
                    for (int i = 0; i < 4; ++i)
                        for (int j = 0; j < 4; ++j)
                            acc[i][j] = __builtin_amdgcn_mfma_f32_16x16x32_bf16(af[i], bfr[j], acc[i][j], 0, 0, 0);
                }
            }

            float bgv[4];
            for (int j = 0; j < 4; ++j) {
                int cidx = colbase + c0w + 16 * j + (lane & 15);
                bgv[j] = (cidx < nbgt) ? 1.f : 0.f;
            }
            int quad = lane >> 4;
            for (int i = 0; i < 4; ++i) {
                for (int reg = 0; reg < 4; ++reg) {
                    float msum = 0.f;
                    for (int j = 0; j < 4; ++j)
                        msum += __expf(acc[i][j][reg] * TEMP_INV) * bgv[j];
                    msum += __shfl_xor(msum, 1);
                    msum += __shfl_xor(msum, 2);
                    msum += __shfl_xor(msum, 4);
                    msum += __shfl_xor(msum, 8);
                    if ((lane & 15) == 0) {
                        int row = rowbase + r0w + 16 * i + quad * 4 + reg;
                        if (row < nfgt) atomicAdd(&negbuf[t * N + row], msum);
                    }
                }
            }
        }
    }
    __threadfence();
    grid.sync();
    __threadfence();

    // ===== Phase E: loss (block 0; wave w handles frames w and w+4) =====
    if (blockIdx.x == 0) {
        float* fl = (float*)smem;
        float* vv = fl + 8;
        __syncthreads();
        int w = tid >> 6;
        for (int t8 = w; t8 < 8; t8 += 4) {
            int nfgt = nfg[t8];
            float s = 0.f;
            for (int k = lane; k < nfgt; k += 64) {
                float pos = __expf(posc[t8 * N + k] * TEMP_INV);
                float ng = negbuf[t8 * N + k];
                s += logf((pos + ng + EPS) / pos);
            }
            for (int o = 32; o > 0; o >>= 1) s += __shfl_down(s, o);
            if (lane == 0) {
                float valid = (nfgt > 0 && nbg[t8] > 0) ? 1.f : 0.f;
                fl[t8] = valid * (s / fmaxf((float)nfgt, 1.f));
                vv[t8] = valid;
            }
        }
        __syncthreads();
        if (tid == 0) {
            float ls = 0.f, v = 0.f;
            for (int i = 0; i < T; ++i) { ls += fl[i]; v += vv[i]; }
            out_loss[0] = (v > 0.f) ? ls / fmaxf(v, 1.f) : 0.f;
        }
    }
}

// ---------------------------------------------------------------------------
extern "C" void kernel_launch(void* const* d_in, const int* in_sizes, int n_in,
                              void* d_out, int out_size, void* d_ws, size_t ws_size,
                              hipStream_t stream) {
    const float* cur  = (const float*)d_in[0];
    const float* hist = (const float*)d_in[1];
    const float* feat = (const float*)d_in[2];
    float* out = (float*)d_out;            // labels[32768] ++ loss[1]
    float* out_loss = out + 32768;
    char* ws = (char*)d_ws;

    // counters region (dstat[32]f + fgc[8] + bgc[8] + ctr[8]) right after rankmap
    size_t zoff = (size_t)T * CAP * C * sizeof(bf16)   // fpack
                + (size_t)T * N * 4                    // negbuf
                + (size_t)T * N * 4                    // posc
                + (size_t)T * N * 2;                   // rankmap
    hipMemsetAsync(ws + zoff, 0, 224, stream);

    static int grid_blocks = 0;
    if (grid_blocks == 0) {
        int dev = 0;
        hipGetDevice(&dev);
        hipDeviceProp_t props;
        hipGetDeviceProperties(&props, dev);
        int nb = 0;
        hipOccupancyMaxActiveBlocksPerMultiprocessor(&nb, mega_kernel, 256, 0);
        if (nb < 1) nb = 1;
        long total = (long)nb * props.multiProcessorCount;
        if (total > 760) total = 760;      // 95 blocks/frame; no need for more
        grid_blocks = (int)(total & ~7L);  // multiple of 8 for frame pinning
        if (grid_blocks < 8) grid_blocks = 8;
    }

    void* args[] = { (void*)&cur, (void*)&hist, (void*)&feat,
                     (void*)&out, (void*)&out_loss, (void*)&ws };
    hipLaunchCooperativeKernel(mega_kernel, dim3(grid_blocks), dim3(256),
                               args, 0, stream);
}

// Round 5
// 150.020 us; speedup vs baseline: 3.3001x; 3.3001x over previous
//
#include <hip/hip_runtime.h>
#include <hip/hip_bf16.h>
#include <cstdint>
#include <cstddef>

// Problem constants
constexpr int T = 8;
constexpr int C = 256;     // feature channels = GEMM K
constexpr int N = 4096;    // H*W pixels per frame
constexpr int CAP = 4232;  // packed rows per frame: >= roundup(nfg,8)+roundup(nbg,128), mult of 8
constexpr float TEMP_INV = 14.285714285714286f;  // 1/0.07
constexpr float EPS = 1e-8f;

typedef __bf16 bf16;
typedef __bf16 bf16x8 __attribute__((ext_vector_type(8)));
typedef float floatx4 __attribute__((ext_vector_type(4)));

// ---------------------------------------------------------------------------
// async global->LDS, 16B per lane, wave-uniform LDS base + lane*16
__device__ __forceinline__ void async_copy16(const bf16* g, bf16* l) {
    __builtin_amdgcn_global_load_lds((const __attribute__((address_space(1))) void*)g,
                                     (__attribute__((address_space(3))) void*)l,
                                     16, 0, 0);
}

// ---------------------------------------------------------------------------
// Fused per-frame dice stats + labels + negbuf zero + rank map + pad zeroing.
// Grid: 8 blocks (one per frame) x 1024 threads.  (unchanged round-0 body)
__global__ void prep_kernel(const float* __restrict__ cur,
                            const float* __restrict__ hist,
                            float* __restrict__ out_labels,
                            float* __restrict__ negbuf,
                            unsigned short* __restrict__ rankmap,
                            bf16* __restrict__ fpack,
                            int* __restrict__ nfg, int* __restrict__ nbg) {
    int t = blockIdx.x;
    int tid = threadIdx.x;
    int lane = tid & 63;
    int w = tid >> 6;

    float cv[4], hv[4];
    float s1 = 0.f, sc = 0.f, sh = 0.f;
    #pragma unroll
    for (int it = 0; it < 4; ++it) {
        int p = it * 1024 + tid;
        float c = cur[t * N + p];
        float h = hist[t * N + p];
        cv[it] = c; hv[it] = h;
        float cb = c > 0.5f ? 1.f : 0.f;
        float hb = h > 0.5f ? 1.f : 0.f;
        s1 += cb * hb; sc += cb; sh += hb;
    }
    for (int o = 32; o > 0; o >>= 1) {
        s1 += __shfl_down(s1, o);
        sc += __shfl_down(sc, o);
        sh += __shfl_down(sh, o);
    }
    __shared__ float r1[16], r2[16], r3[16];
    __shared__ float uflag;
    __shared__ int cfg_s, cbg_s;
    if (lane == 0) { r1[w] = s1; r2[w] = sc; r3[w] = sh; }
    if (tid == 0) { cfg_s = 0; cbg_s = 0; }
    __syncthreads();
    if (tid == 0) {
        float e1 = 0.f, scs = 0.f, shs = 0.f;
        for (int i = 0; i < 16; ++i) { e1 += r1[i]; scs += r2[i]; shs += r3[i]; }
        float e2 = scs + shs;
        float m1 = (2.f * e1 + EPS) / (e2 + EPS);
        float m2 = (e1 + EPS) / (e2 - e1 + EPS);
        float dev = 1.f - 0.5f * (m1 + m2);
        uflag = (dev <= 0.0f) ? 1.f : 0.f;
    }
    __syncthreads();
    bool use_curr = uflag != 0.f;
    for (int it = 0; it < 4; ++it) {
        int p = it * 1024 + tid;
        int gi = t * N + p;
        float lab = use_curr ? cv[it] : hv[it];
        out_labels[gi] = lab;
        negbuf[gi] = 0.f;
        bool fg = lab > 0.5f;
        unsigned long long b = __ballot(fg);
        unsigned long long lowmask = (lane == 63) ? 0x7fffffffffffffffull
                                                  : ((1ull << lane) - 1ull);
        int rank_fg = __popcll(b & lowmask);
        int rank_bg = __popcll((~b) & lowmask);
        int cnt_fg = __popcll(b);
        int base_fg = 0, base_bg = 0;
        if (lane == 0) {
            base_fg = atomicAdd(&cfg_s, cnt_fg);
            base_bg = atomicAdd(&cbg_s, 64 - cnt_fg);
        }
        base_fg = __shfl(base_fg, 0);
        base_bg = __shfl(base_bg, 0);
        int rank = fg ? (base_fg + rank_fg) : (base_bg + rank_bg);
        rankmap[gi] = (unsigned short)(rank | (fg ? 0x8000 : 0));
    }
    __syncthreads();
    if (tid == 0) { nfg[t] = cfg_s; nbg[t] = cbg_s; }
    // zero pad rows [N, CAP) of this frame's packed array (covers B-tile overreads)
    float4 z4 = make_float4(0.f, 0.f, 0.f, 0.f);
    float4* pz = (float4*)(fpack + ((size_t)t * CAP + N) * C);
    int chunks = (CAP - N) * (C / 8);          // 16B chunks
    for (int i = tid; i < chunks; i += 1024) pz[i] = z4;
}

// ---------------------------------------------------------------------------
// Normalize features, cast bf16, and SCATTER each pixel row to its compacted
// position in fpack (fg ranks first, bg ranks at roundup(nfg,8)), applying the
// XOR-chunk swizzle at the store so sim's staging reads are fully contiguous.
// Round-5 change: FRAME -> XCD PINNING.  t = blockIdx.x & 7 (was >> 6) so that
// frame f's fpack lines are written (left dirty) in XCD f's L2 -- the same XCD
// sim reads them from (sim uses t = blockIdx.x & 7).  Index permutation only.
__global__ __launch_bounds__(256, 4) void normalize_kernel(const float* __restrict__ feat,
                                                           const unsigned short* __restrict__ rankmap,
                                                           const int* __restrict__ nfg,
                                                           bf16* __restrict__ fpack,
                                                           float* __restrict__ posc) {
    __shared__ bf16 tile[64 * 258];    // [n][c], true chunk order, pad 258
    __shared__ float partial[256];
    __shared__ float rnorm_s[64];
    __shared__ unsigned short rk_s[64];
    __shared__ int bbase_s;
    int t = blockIdx.x & 7;            // frame -> XCD pin (matches sim)
    int n0 = (blockIdx.x >> 3) * 64;   // 64 pixel rows per block (0..63 -> full frame)
    int tid = threadIdx.x;
    int lane63 = tid & 63;             // pixel within tile
    int w = tid >> 6;                  // wave -> 64-channel slab
    if (tid == 0) bbase_s = (nfg[t] + 7) & ~7;
    if (tid < 64) rk_s[tid] = rankmap[t * N + n0 + tid];
    const float* fb = feat + (size_t)t * C * N;
    float ss = 0.f;
    #pragma unroll 16
    for (int it = 0; it < 64; ++it) {
        int c = w * 64 + it;
        float v = fb[(size_t)c * N + n0 + lane63];
        ss += v * v;
        tile[lane63 * 258 + c] = (bf16)v;
    }
    partial[tid] = ss;
    __syncthreads();
    if (tid < 64) {
        float s = partial[tid] + partial[tid + 64] + partial[tid + 128] + partial[tid + 192];
        float r = 1.f / fmaxf(sqrtf(s), 1e-12f);
        rnorm_s[tid] = r;
        unsigned short rk = rk_s[tid];
        if (rk & 0x8000) posc[t * N + (rk & 0x7fff)] = s * r * r;  // fg only
    }
    __syncthreads();
    int bbase = bbase_s;
    bf16* fp = fpack + (size_t)t * CAP * C;
    #pragma unroll
    for (int it = 0; it < 8; ++it) {
        int l = it * 256 + tid;        // short8 index, 0..2047
        int n = l >> 5;                // tile row (pixel)
        int c8 = l & 31;               // true 16B-chunk index 0..31
        unsigned short rk = rk_s[n];
        int r_pack = (rk & 0x7fff) + ((rk & 0x8000) ? 0 : bbase);
        int slot = (c8 & ~7) | ((c8 & 7) ^ (r_pack & 7));   // swizzled store pos
        float r = rnorm_s[n];
        bf16x8 vin = *(const bf16x8*)&tile[n * 258 + c8 * 8];
        bf16x8 vo;
        for (int j = 0; j < 8; ++j) vo[j] = (bf16)((float)vin[j] * r);
        *(bf16x8*)(fp + (size_t)r_pack * C + slot * 8) = vo;
    }
}

// ---------------------------------------------------------------------------
// Fused sim GEMM + exp + row reduction over compacted fg rows x bg cols.
// Proven round-0 inner structure (single-buffer 32KB LDS, swizzled contiguous
// staging, 3 blocks/CU).  Round-5 change: grid trimmed 8192 -> 2176 with a
// runtime nr x nc tile map (ceil(nfg/128)*ceil(nbg/128) <= 272 since
// nfg+nbg = 4096), removing ~6k no-op block dispatches.
__global__ __launch_bounds__(256, 3) void sim_kernel(const bf16* __restrict__ fpack,
                                                     const int* __restrict__ nfg,
                                                     const int* __restrict__ nbg,
                                                     float* __restrict__ neg) {
    int t = blockIdx.x & 7;            // frame -> XCD pin (8 XCDs)
    int wid = blockIdx.x >> 3;         // 0..271
    int nfgt = nfg[t];
    int nbgt = nbg[t];
    if (nfgt <= 0 || nbgt <= 0) return;
    int nr = (nfgt + 127) >> 7;
    int nc = (nbgt + 127) >> 7;
    if (wid >= nr * nc) return;
    int rowbase = (wid / nc) * 128;
    int colbase = (wid % nc) * 128;
    int bbase = (nfgt + 7) & ~7;       // packed row where bg rows start

    __shared__ bf16 a_lds[128 * 64];
    __shared__ bf16 b_lds[128 * 64];
    int tid = threadIdx.x;
    int lane = tid & 63;
    int w = tid >> 6;
    const bf16* fb = fpack + (size_t)t * CAP * C;

    int lrow = lane >> 3;              // row within 8-row group
    int lchunk = lane & 7;             // 16B chunk within 128B subrow
    int r0w = (w & 1) * 64;
    int c0w = (w >> 1) * 64;

    floatx4 acc[4][4];
    for (int i = 0; i < 4; ++i)
        for (int j = 0; j < 4; ++j)
            acc[i][j] = (floatx4){0.f, 0.f, 0.f, 0.f};

    for (int ks = 0; ks < 4; ++ks) {
        int k0 = ks * 64;
        __syncthreads();
        for (int s = 0; s < 4; ++s) {
            int q = w * 4 + s;                 // 0..15
            int ra = rowbase + q * 8 + lrow;           // contiguous packed fg row
            int rb = bbase + colbase + q * 8 + lrow;   // contiguous packed bg row
            async_copy16(fb + (size_t)ra * C + k0 + lchunk * 8, &a_lds[q * 512]);
            async_copy16(fb + (size_t)rb * C + k0 + lchunk * 8, &b_lds[q * 512]);
        }
        __syncthreads();
        for (int kk = 0; kk < 64; kk += 32) {
            int quad = lane >> 4;
            int chread = (kk >> 3) + quad;     // wanted true chunk (0..7)
            bf16x8 af[4], bfr[4];
            for (int i = 0; i < 4; ++i) {
                int r = r0w + 16 * i + (lane & 15);
                int chs = chread ^ (r & 7);
                af[i] = *(const bf16x8*)&a_lds[r * 64 + chs * 8];
            }
            for (int j = 0; j < 4; ++j) {
                int cidx = c0w + 16 * j + (lane & 15);
                int chs = chread ^ (cidx & 7);
                bfr[j] = *(const bf16x8*)&b_lds[cidx * 64 + chs * 8];
            }
            for (int i = 0; i < 4; ++i)
                for (int j = 0; j < 4; ++j)
                    acc[i][j] = __builtin_amdgcn_mfma_f32_16x16x32_bf16(af[i], bfr[j], acc[i][j], 0, 0, 0);
        }
    }

    // epilogue: exp + row-sum; mask padded cols, guard padded rows
    float bgv[4];
    for (int j = 0; j < 4; ++j) {
        int cidx = colbase + c0w + 16 * j + (lane & 15);
        bgv[j] = (cidx < nbgt) ? 1.f : 0.f;
    }
    int quad = lane >> 4;
    for (int i = 0; i < 4; ++i) {
        for (int reg = 0; reg < 4; ++reg) {
            float msum = 0.f;
            for (int j = 0; j < 4; ++j)
                msum += __expf(acc[i][j][reg] * TEMP_INV) * bgv[j];
            msum += __shfl_xor(msum, 1);
            msum += __shfl_xor(msum, 2);
            msum += __shfl_xor(msum, 4);
            msum += __shfl_xor(msum, 8);
            if ((lane & 15) == 0) {
                int row = rowbase + r0w + 16 * i + quad * 4 + reg;   // compacted fg row
                if (row < nfgt) atomicAdd(&neg[t * N + row], msum);
            }
        }
    }
}

// ---------------------------------------------------------------------------
// Fused per-frame + final loss: 512 threads, wave t handles frame t.
// All reads contiguous (neg and pos both compacted by fg rank).  (unchanged)
__global__ void loss_kernel(const float* __restrict__ negbuf,
                            const float* __restrict__ posc,
                            const int* __restrict__ nfg,
                            const int* __restrict__ nbg,
                            float* __restrict__ out_loss) {
    int tid = threadIdx.x;
    int t = tid >> 6;
    int lane = tid & 63;
    int nfgt = nfg[t];
    float s = 0.f;
    #pragma unroll 4
    for (int k = lane; k < nfgt; k += 64) {
        float pos = __expf(posc[t * N + k] * TEMP_INV);
        float ng = negbuf[t * N + k];
        s += logf((pos + ng + EPS) / pos);
    }
    for (int o = 32; o > 0; o >>= 1) s += __shfl_down(s, o);
    __shared__ float fl[8], vv[8];
    if (lane == 0) {
        float valid = (nfgt > 0 && nbg[t] > 0) ? 1.f : 0.f;
        fl[t] = valid * (s / fmaxf((float)nfgt, 1.f));
        vv[t] = valid;
    }
    __syncthreads();
    if (tid == 0) {
        float ls = 0.f, v = 0.f;
        for (int i = 0; i < T; ++i) { ls += fl[i]; v += vv[i]; }
        out_loss[0] = (v > 0.f) ? ls / fmaxf(v, 1.f) : 0.f;
    }
}

// ---------------------------------------------------------------------------
extern "C" void kernel_launch(void* const* d_in, const int* in_sizes, int n_in,
                              void* d_out, int out_size, void* d_ws, size_t ws_size,
                              hipStream_t stream) {
    const float* cur  = (const float*)d_in[0];
    const float* hist = (const float*)d_in[1];
    const float* feat = (const float*)d_in[2];
    float* out = (float*)d_out;   // labels[32768] ++ loss[1]

    char* ws = (char*)d_ws;
    bf16*  fpack   = (bf16*)ws;                           // T*CAP*C bf16 = 17.33 MB
    size_t off = (size_t)T * CAP * C * sizeof(bf16);      // 17334272
    float* negbuf  = (float*)(ws + off);  off += (size_t)T * N * 4;   // 131072
    float* posc    = (float*)(ws + off);  off += (size_t)T * N * 4;   // 131072
    unsigned short* rankmap = (unsigned short*)(ws + off); off += (size_t)T * N * 2;
    int*   nfg     = (int*)(ws + off);
    int*   nbg     = nfg + 8;

    prep_kernel<<<8, 1024, 0, stream>>>(cur, hist, out, negbuf, rankmap, fpack, nfg, nbg);
    normalize_kernel<<<512, 256, 0, stream>>>(feat, rankmap, nfg, fpack, posc);
    sim_kernel<<<2176, 256, 0, stream>>>(fpack, nfg, nbg, negbuf);
    loss_kernel<<<1, 512, 0, stream>>>(negbuf, posc, nfg, nbg, out + 32768);
}